// Round 9
// baseline (253.430 us; speedup 1.0000x reference)
//
#include <hip/hip_runtime.h>
#include <hip/hip_bf16.h>

// Problem: B=2, S=2048, D_MODEL=1024, H=16, DK=64.
// out = ((l2norm(Q Wq^T) l2norm(K Wk^T)^T)^2 (V Wv^T)) Wo^T   (per head)
// fp32 in/out; internally bf16 MFMA with fp32 accumulation.
//
// Round 9 changes vs round 8:
//  - attn PV: waves partition (q-half x j-half) quadrants. V^T read 2x (was
//    4x), P read exactly once via 16B-granular XOR swizzle (b128 aa reads).
//    One-time df-panel exchange through staging LDS at block end.
//  - qkv/wo: BK=32 (LDS 32/24 KB dbuf) -> qkv fits 3 blocks/CU exactly
//    (768 grid; was 2/CU with a half-idle tail round). Swizzle
//    f(row)=(row^(row>>2))&3 keeps reads <=2-way. V-transpose (MODE2) now
//    direct global us4 scatter (full 128B line coverage per wave -> L2
//    merges); no LDS transpose buffer.

#define D_MODEL 1024
#define N_HEADS 16
#define D_K     64
#define BATCH   2
#define SEQ     2048
#define M_TOT   (BATCH * SEQ)   // 4096

typedef short  s16x8 __attribute__((ext_vector_type(8)));   // 8 bf16 = 4 VGPR
typedef float  f32x4 __attribute__((ext_vector_type(4)));   // MFMA C/D frag
typedef unsigned short ushort_t;
typedef ushort_t us4 __attribute__((ext_vector_type(4)));

__device__ __forceinline__ ushort_t f2bf(float f) {
    union { float f; unsigned int u; } x; x.f = f;
    unsigned int u = x.u;
    return (ushort_t)((u + 0x7fffu + ((u >> 16) & 1u)) >> 16);  // RNE
}
__device__ __forceinline__ float bf2f(ushort_t h) {
    union { unsigned int u; float f; } x; x.u = ((unsigned int)h) << 16;
    return x.f;
}
// pack two fp32 -> u32 of two bf16 (RNE)
__device__ __forceinline__ unsigned int pack2bf(float a, float b) {
    union { __hip_bfloat162 h; unsigned int u; } x;
    x.h = __float22bfloat162_rn(float2{a, b});
    return x.u;
}

// async global->LDS, 16B per lane (lane i's lds ptr == wave base + i*16).
__device__ __forceinline__ void gload_lds16(const ushort_t* g, ushort_t* l) {
    __builtin_amdgcn_global_load_lds(
        (__attribute__((address_space(1))) void*)(ushort_t*)g,
        (__attribute__((address_space(3))) void*)l, 16, 0, 0);
}

#define WAIT_VM(n)  asm volatile("s_waitcnt vmcnt(" #n ")" ::: "memory")
#define WAIT_LGKM0  asm volatile("s_waitcnt lgkmcnt(0)" ::: "memory")
#define BARRIER     asm volatile("s_barrier" ::: "memory")

// ---------------------------------------------------------------------------
// fp32 -> bf16 conversion, all 11 inputs in one launch (blockIdx.y = tensor).
// ---------------------------------------------------------------------------
struct ConvArgs {
    const float* src[11];
    ushort_t*    dst[11];
    int          n[11];
};

__global__ __launch_bounds__(256) void convert_kernel(ConvArgs a) {
    const int t = blockIdx.y;
    const int i = (blockIdx.x * 256 + threadIdx.x) * 4;
    if (i >= a.n[t]) return;
    const float4 v = *(const float4*)(a.src[t] + i);
    us4 p;
    p[0] = f2bf(v.x); p[1] = f2bf(v.y); p[2] = f2bf(v.z); p[3] = f2bf(v.w);
    *(us4*)(a.dst[t] + i) = p;
}

// ---------------------------------------------------------------------------
// GEMM body: BM x 128 tile, 4 waves 2x2, 2-deep DMA pipeline, BK=32.
// Per-wave DMAs per tile: BM=128 -> 4 (2 A + 2 B), BM=64 -> 3 (1 A + 2 B).
// Row swizzle f(row) = (row ^ (row>>2)) & 3 on 8-ushort chunks.
// MODE 0: fp32 row-major store   MODE 1: L2-norm -> (B,H,S,DK) bf16
// MODE 2: direct transposed scatter -> (B,H,DK,S) bf16
// ---------------------------------------------------------------------------
template <int BM, int MODE>
__device__ __forceinline__ void gemm_body(
    ushort_t* __restrict__ smem,
    const ushort_t* __restrict__ A,
    const ushort_t* __restrict__ W,
    const ushort_t* __restrict__ bias,
    ushort_t* __restrict__ out,
    float* __restrict__ outf,
    int bx, int by)
{
    static_assert(BM == 64 || BM == 128, "");
    constexpr int K     = 1024;
    constexpr int MF    = BM / 32;
    constexpr int BUFW  = (BM + 128) * 32;   // words per LDS buffer
    constexpr int NIT   = K / 32;            // 32
    constexpr int APASS = (BM * 32) / 2048;  // 2 or 1

    const int t    = threadIdx.x;
    const int wave = t >> 6;
    const int lane = t & 63;
    const int quad = lane >> 4;
    const int lc   = lane & 15;
    const int wm   = wave >> 1;
    const int wn   = wave & 1;
    const int m0   = bx * BM;
    const int n0   = by * 128;
    const int flc  = (lc & 3) ^ ((lc >> 2) & 3);  // f(row) for frag rows

    f32x4 acc[MF][4];
    const f32x4 zero = {0.f, 0.f, 0.f, 0.f};
#pragma unroll
    for (int i = 0; i < MF; ++i)
#pragma unroll
        for (int j = 0; j < 4; ++j) acc[i][j] = zero;

    auto stage = [&](int buf, int k0) {
        ushort_t* Ast = smem + buf * BUFW;
        ushort_t* Bst = Ast + BM * 32;
#pragma unroll
        for (int c = 0; c < APASS; ++c) {
            int idx = c * 256 + t;
            int row = idx >> 2, phys = idx & 3;
            int col = ((phys ^ ((row ^ (row >> 2)))) & 3) * 8;
            gload_lds16(A + (size_t)(m0 + row) * K + k0 + col, Ast + idx * 8);
        }
#pragma unroll
        for (int c = 0; c < 2; ++c) {
            int idx = c * 256 + t;
            int row = idx >> 2, phys = idx & 3;
            int col = ((phys ^ ((row ^ (row >> 2)))) & 3) * 8;
            gload_lds16(W + (size_t)(n0 + row) * K + k0 + col, Bst + idx * 8);
        }
    };
    auto comp = [&](int buf) {
        ushort_t* Ast = smem + buf * BUFW;
        ushort_t* Bst = Ast + BM * 32;
        const int ph = ((quad ^ flc) & 3) * 8;
        s16x8 a[MF], b[4];
#pragma unroll
        for (int i = 0; i < MF; ++i)
            a[i] = *(const s16x8*)(Ast + (wm * (BM / 2) + i * 16 + lc) * 32 + ph);
#pragma unroll
        for (int i = 0; i < 4; ++i)
            b[i] = *(const s16x8*)(Bst + (wn * 64 + i * 16 + lc) * 32 + ph);
#pragma unroll
        for (int mf = 0; mf < MF; ++mf)
#pragma unroll
            for (int nf = 0; nf < 4; ++nf)
                acc[mf][nf] = __builtin_amdgcn_mfma_f32_16x16x32_bf16(
                    a[mf], b[nf], acc[mf][nf], 0, 0, 0);
    };

    stage(0, 0);
    stage(1, 32);
    for (int it = 0; it < NIT - 2; ++it) {
        if constexpr (BM == 128) WAIT_VM(4); else WAIT_VM(3);
        BARRIER;                  // tile `it` fully landed
        comp(it & 1);
        WAIT_LGKM0;
        BARRIER;                  // all waves done reading buf(it&1)
        stage(it & 1, (it + 2) * 32);
    }
    if constexpr (BM == 128) WAIT_VM(4); else WAIT_VM(3);
    BARRIER;
    comp((NIT - 2) & 1);
    WAIT_VM(0);
    BARRIER;
    comp((NIT - 1) & 1);

    float bv[4];
#pragma unroll
    for (int nf = 0; nf < 4; ++nf) bv[nf] = bf2f(bias[n0 + wn * 64 + nf * 16 + lc]);

    if (MODE == 0) {
#pragma unroll
        for (int mf = 0; mf < MF; ++mf)
#pragma unroll
            for (int nf = 0; nf < 4; ++nf)
#pragma unroll
                for (int r = 0; r < 4; ++r) {
                    int mg = m0 + wm * (BM / 2) + mf * 16 + quad * 4 + r;
                    int ng = n0 + wn * 64 + nf * 16 + lc;
                    outf[(size_t)mg * D_MODEL + ng] = acc[mf][nf][r] + bv[nf];
                }
    } else if (MODE == 1) {
        // wave's 64 cols == one head; row-of-64 lives in 16 lanes x 4 nf regs
#pragma unroll
        for (int mf = 0; mf < MF; ++mf)
#pragma unroll
            for (int r = 0; r < 4; ++r) {
                float ss = 0.f;
#pragma unroll
                for (int nf = 0; nf < 4; ++nf) {
                    float v = acc[mf][nf][r] + bv[nf];
                    acc[mf][nf][r] = v;
                    ss += v * v;
                }
                ss += __shfl_xor(ss, 1);
                ss += __shfl_xor(ss, 2);
                ss += __shfl_xor(ss, 4);
                ss += __shfl_xor(ss, 8);
                float inv = rsqrtf(ss + 1e-8f);
                int mg = m0 + wm * (BM / 2) + mf * 16 + quad * 4 + r;
                int b  = mg >> 11;
                int s  = mg & 2047;
#pragma unroll
                for (int nf = 0; nf < 4; ++nf) {
                    int ng = n0 + wn * 64 + nf * 16 + lc;
                    int h = ng >> 6, d = ng & 63;
                    out[(((size_t)(b * N_HEADS + h)) * SEQ + s) * D_K + d] =
                        f2bf(acc[mf][nf][r] * inv);
                }
            }
    } else {
        // MODE 2: direct transposed scatter. Lane stores us4 along s at
        // (b,h,d,s). A wave's 16 (mf,quad) s-offsets tile a full 128B line
        // per d -> L2 merges to full lines.
#pragma unroll
        for (int mf = 0; mf < 4; ++mf)
#pragma unroll
            for (int nf = 0; nf < 4; ++nf) {
                us4 p;
#pragma unroll
                for (int r = 0; r < 4; ++r) p[r] = f2bf(acc[mf][nf][r] + bv[nf]);
                int mg = m0 + wm * 64 + mf * 16 + quad * 4;
                int b  = mg >> 11;
                int s  = mg & 2047;
                int ng = n0 + wn * 64 + nf * 16 + lc;
                int h = ng >> 6, dh = ng & 63;
                *(us4*)(out + (((size_t)(b * N_HEADS + h)) * D_K + dh) * SEQ + s) = p;
            }
    }
}

// fused Q/K/V projections: grid.z selects tensor (768 blocks = 3/CU)
__global__ __launch_bounds__(256) void qkv_kernel(
    const ushort_t* __restrict__ Qb, const ushort_t* __restrict__ Kb,
    const ushort_t* __restrict__ Vb,
    const ushort_t* __restrict__ Wq, const ushort_t* __restrict__ Wk,
    const ushort_t* __restrict__ Wv,
    const ushort_t* __restrict__ bq, const ushort_t* __restrict__ bk,
    const ushort_t* __restrict__ bv,
    ushort_t* __restrict__ qn, ushort_t* __restrict__ kn,
    ushort_t* __restrict__ vT)
{
    __shared__ __align__(16) ushort_t smem[2 * (128 + 128) * 32];  // 32 KB
    const int z = blockIdx.z;
    if (z == 0)
        gemm_body<128, 1>(smem, Qb, Wq, bq, qn, nullptr, blockIdx.x, blockIdx.y);
    else if (z == 1)
        gemm_body<128, 1>(smem, Kb, Wk, bk, kn, nullptr, blockIdx.x, blockIdx.y);
    else
        gemm_body<128, 2>(smem, Vb, Wv, bv, vT, nullptr, blockIdx.x, blockIdx.y);
}

// output projection: BM=64 -> 512 blocks = 2/CU
__global__ __launch_bounds__(256) void wo_kernel(
    const ushort_t* __restrict__ A, const ushort_t* __restrict__ W,
    const ushort_t* __restrict__ bias, float* __restrict__ outf)
{
    __shared__ __align__(16) ushort_t smem[2 * (64 + 128) * 32];   // 24 KB
    gemm_body<64, 0>(smem, A, W, bias, nullptr, outf, blockIdx.x, blockIdx.y);
}

// ---------------------------------------------------------------------------
// Attention: per (b,h): out = (qn kn^T)^2 v.
// Grid (x=bh 32, y=qt 16) -> 512 blocks; bh%8 pins a head to one XCD's L2.
// 128 q/block. Per 64-j k-tile:
//   QK^T: wave w owns j-slice [w*16,+16): S^T = K_slice . Q^T (K=32);
//         square+pack -> shared P[128q][64j], 16B-granular XOR swizzle.
//   PV:   wave (qh=w>>1, jh=w&1) owns q-half x j-half: K=32 over 32 j.
//         aa: 4 b128 from P (read exactly once); bvf: 4 b128 (V read 2x).
//   Epilogue: df-panel exchange via staging LDS; all 4 waves store.
// ---------------------------------------------------------------------------
__global__ __launch_bounds__(256) void attn_kernel(
    const ushort_t* __restrict__ qn,
    const ushort_t* __restrict__ kn,
    const ushort_t* __restrict__ vT,
    ushort_t* __restrict__ attn_out)
{
    // staging buf i at smem+i*8192: kst [64 j][64 dk] + vst [64 d][64 j]
    __shared__ __align__(16) ushort_t smem[2 * 8192];   // 32 KB (also epilogue)
    __shared__ __align__(16) ushort_t Pl[128 * 64];     // 16 KB, swizzled

    const int t    = threadIdx.x;
    const int wave = t >> 6;
    const int lane = t & 63;
    const int quad = lane >> 4;
    const int lc   = lane & 15;
    const int bh   = blockIdx.x;       // 0..31 (bh%8 -> XCD pin)
    const int qt   = blockIdx.y;       // 0..15
    const int b    = bh >> 4;
    const int h    = bh & 15;
    const int qh   = wave >> 1;        // q-half for PV
    const int jh   = wave & 1;         // j-half for PV

    const ushort_t* qb = qn + (size_t)bh * SEQ * D_K;
    const ushort_t* kb = kn + (size_t)bh * SEQ * D_K;
    const ushort_t* vb = vT + (size_t)bh * D_K * SEQ;
    const int q0 = qt * 128;

    // Q B-frags for all 8 q-tiles of this block, reused over 32 k-tiles
    s16x8 qf[8][2];
#pragma unroll
    for (int mf = 0; mf < 8; ++mf)
#pragma unroll
        for (int ks = 0; ks < 2; ++ks)
            qf[mf][ks] = *(const s16x8*)(qb + (size_t)(q0 + mf * 16 + lc) * D_K +
                                         ks * 32 + quad * 8);

    f32x4 oacc[4][4];                  // [mfp(q within half)][df] j-half partial
    const f32x4 zero = {0.f, 0.f, 0.f, 0.f};
#pragma unroll
    for (int mf = 0; mf < 4; ++mf)
#pragma unroll
        for (int df = 0; df < 4; ++df) oacc[mf][df] = zero;

    auto stage = [&](int buf, int j0) {
        ushort_t* kst = smem + buf * 8192;
        ushort_t* vst = kst + 4096;
#pragma unroll
        for (int c = 0; c < 2; ++c) {
            int idx = c * 256 + t;
            int row = idx >> 3, phys = idx & 7;
            int col = (phys ^ (row & 7)) * 8;
            gload_lds16(kb + (size_t)(j0 + row) * D_K + col, kst + idx * 8);
            gload_lds16(vb + (size_t)row * SEQ + j0 + col, vst + idx * 8);
        }
    };

    // QK^T: wave's 16-j slice vs all 128 q -> P (16B-swizzled)
    const int pwoff = (((wave * 2 + (quad >> 1)) ^ (lc & 7)) * 8) + (quad & 1) * 4;
    auto qk = [&](int buf) {
        ushort_t* kst = smem + buf * 8192;
        s16x8 ak[2];
#pragma unroll
        for (int ks = 0; ks < 2; ++ks)
            ak[ks] = *(const s16x8*)(kst + (wave * 16 + lc) * 64 +
                                     (((ks * 4 + quad) ^ (lc & 7)) * 8));
#pragma unroll
        for (int mf = 0; mf < 8; ++mf) {
            f32x4 st = zero;   // S^T tile: lane = [j=quad*4+r][q=lc]
#pragma unroll
            for (int ks = 0; ks < 2; ++ks)
                st = __builtin_amdgcn_mfma_f32_16x16x32_bf16(ak[ks], qf[mf][ks], st, 0, 0, 0);
            uint2 w;
            w.x = pack2bf(st[0] * st[0], st[1] * st[1]);
            w.y = pack2bf(st[2] * st[2], st[3] * st[3]);
            *(uint2*)(Pl + (mf * 16 + lc) * 64 + pwoff) = w;
        }
    };

    // PV: wave's (q-half, j-half) quadrant, K=32
    auto pv = [&](int buf) {
        ushort_t* vst = smem + buf * 8192 + 4096;
        s16x8 bvf[4];
#pragma unroll
        for (int df = 0; df < 4; ++df)
            bvf[df] = *(const s16x8*)(vst + (df * 16 + lc) * 64 +
                                      (((jh * 4 + quad) ^ (lc & 7)) * 8));
        s16x8 aa[4];
#pragma unroll
        for (int mfp = 0; mfp < 4; ++mfp) {
            const int row = qh * 64 + mfp * 16 + lc;
            aa[mfp] = *(const s16x8*)(Pl + row * 64 +
                                      (((jh * 4 + quad) ^ (lc & 7)) * 8));
        }
#pragma unroll
        for (int mfp = 0; mfp < 4; ++mfp)
#pragma unroll
            for (int df = 0; df < 4; ++df)
                oacc[mfp][df] = __builtin_amdgcn_mfma_f32_16x16x32_bf16(
                    aa[mfp], bvf[df], oacc[mfp][df], 0, 0, 0);
    };

    constexpr int NT = 32;
    stage(0, 0);
    stage(1, 64);
    for (int it = 0; it < NT; ++it) {
        if (it < NT - 1) { WAIT_VM(4); } else { WAIT_VM(0); }
        BARRIER;                       // k/v tile `it` landed everywhere
        qk(it & 1);
        WAIT_LGKM0;
        BARRIER;                       // P complete; kst reads done
        pv(it & 1);
        if (it < NT - 2) {
            WAIT_LGKM0;
            BARRIER;                   // vst + P reads done -> buf reusable
            stage(it & 1, (it + 2) * 64);
        } else if (it == NT - 2) {
            WAIT_LGKM0;
            BARRIER;                   // protect P for the last qk()
        }
    }

    // cross-wave j-half reduction: each wave gives away 2 df panels, keeps 2.
    // regions: [qh*2 + half][64 q][32 d] fp32 in the 32 KB staging area.
    __syncthreads();
    float* red = (float*)smem;
    {
        const int reg = qh * 2 + (jh ^ 1);
        const int dfb = (jh ^ 1) * 2;
#pragma unroll
        for (int mfp = 0; mfp < 4; ++mfp)
#pragma unroll
            for (int dd = 0; dd < 2; ++dd)
#pragma unroll
                for (int r = 0; r < 4; ++r)
                    red[reg * 2048 + (mfp * 16 + quad * 4 + r) * 32 + dd * 16 + lc] =
                        oacc[mfp][dfb + dd][r];
    }
    __syncthreads();
    {
        const int reg = qh * 2 + jh;
        const int dfb = jh * 2;
#pragma unroll
        for (int mfp = 0; mfp < 4; ++mfp)
#pragma unroll
            for (int dd = 0; dd < 2; ++dd)
#pragma unroll
                for (int r = 0; r < 4; ++r) {
                    float v = oacc[mfp][dfb + dd][r] +
                              red[reg * 2048 + (mfp * 16 + quad * 4 + r) * 32 + dd * 16 + lc];
                    int s = q0 + qh * 64 + mfp * 16 + quad * 4 + r;
                    int d = (dfb + dd) * 16 + lc;
                    attn_out[((size_t)(b * SEQ + s)) * D_MODEL + h * D_K + d] = f2bf(v);
                }
    }
}

extern "C" void kernel_launch(void* const* d_in, const int* in_sizes, int n_in,
                              void* d_out, int out_size, void* d_ws, size_t ws_size,
                              hipStream_t stream)
{
    const float* Qf   = (const float*)d_in[0];
    const float* Kf   = (const float*)d_in[1];
    const float* Vf   = (const float*)d_in[2];
    const float* Wqf  = (const float*)d_in[3];
    const float* Wqbf = (const float*)d_in[4];
    const float* Wkf  = (const float*)d_in[5];
    const float* Wkbf = (const float*)d_in[6];
    const float* Wvf  = (const float*)d_in[7];
    const float* Wvbf = (const float*)d_in[8];
    const float* Wof  = (const float*)d_in[9];
    const float* Wobf = (const float*)d_in[10];

    const size_t NM = (size_t)M_TOT * D_MODEL;
    const size_t NW = (size_t)D_MODEL * D_MODEL;
    const size_t NB = D_MODEL;

    ushort_t* p = (ushort_t*)d_ws;
    ushort_t* Qb  = p;  p += NM;
    ushort_t* Kb  = p;  p += NM;
    ushort_t* Vb  = p;  p += NM;
    ushort_t* Wq  = p;  p += NW;
    ushort_t* Wk  = p;  p += NW;
    ushort_t* Wv  = p;  p += NW;
    ushort_t* Wo  = p;  p += NW;
    ushort_t* bq  = p;  p += NB;
    ushort_t* bk  = p;  p += NB;
    ushort_t* bvv = p;  p += NB;
    ushort_t* bo  = p;  p += NB;
    ushort_t* qn  = p;  p += NM;   // (B,H,S,DK)
    ushort_t* kn  = p;  p += NM;   // (B,H,S,DK)
    ushort_t* vT  = p;  p += NM;   // (B,H,DK,S)
    ushort_t* ao  = p;  p += NM;   // (B,S,D)

    ConvArgs ca;
    ca.src[0] = Qf;   ca.dst[0] = Qb;  ca.n[0] = (int)NM;
    ca.src[1] = Kf;   ca.dst[1] = Kb;  ca.n[1] = (int)NM;
    ca.src[2] = Vf;   ca.dst[2] = Vb;  ca.n[2] = (int)NM;
    ca.src[3] = Wqf;  ca.dst[3] = Wq;  ca.n[3] = (int)NW;
    ca.src[4] = Wkf;  ca.dst[4] = Wk;  ca.n[4] = (int)NW;
    ca.src[5] = Wvf;  ca.dst[5] = Wv;  ca.n[5] = (int)NW;
    ca.src[6] = Wof;  ca.dst[6] = Wo;  ca.n[6] = (int)NW;
    ca.src[7] = Wqbf; ca.dst[7] = bq;  ca.n[7] = (int)NB;
    ca.src[8] = Wkbf; ca.dst[8] = bk;  ca.n[8] = (int)NB;
    ca.src[9] = Wvbf; ca.dst[9] = bvv; ca.n[9] = (int)NB;
    ca.src[10] = Wobf; ca.dst[10] = bo; ca.n[10] = (int)NB;

    dim3 blk(256);
    convert_kernel<<<dim3((unsigned)(NM / (256 * 4)), 11), blk, 0, stream>>>(ca);

    qkv_kernel<<<dim3(M_TOT / 128, D_MODEL / 128, 3), blk, 0, stream>>>(
        Qb, Kb, Vb, Wq, Wk, Wv, bq, bk, bvv, qn, kn, vT);
    attn_kernel<<<dim3(BATCH * N_HEADS, SEQ / 128), blk, 0, stream>>>(qn, kn, vT, ao);
    wo_kernel<<<dim3(M_TOT / 64, D_MODEL / 128), blk, 0, stream>>>(
        ao, Wo, bo, (float*)d_out);
}

// Round 10
// 244.962 us; speedup vs baseline: 1.0346x; 1.0346x over previous
//
#include <hip/hip_runtime.h>
#include <hip/hip_bf16.h>

// Problem: B=2, S=2048, D_MODEL=1024, H=16, DK=64.
// out = ((l2norm(Q Wq^T) l2norm(K Wk^T)^T)^2 (V Wv^T)) Wo^T   (per head)
// fp32 in/out; internally bf16 MFMA with fp32 accumulation.
//
// Round 10: REVERT gemm_body to the R8 configuration (BK=64, 2-deep vmcnt
// pipeline, 64/48 KB LDS, LDS MODE2 transpose). R9's BK=32 halved the
// compute quantum per barrier below the DMA round-trip -> latency-bound
// (qkv 50->83us, MfmaUtil 11.5%) and its swizzle produced 3.1M conflicts.
// KEEP R9's attn (quadrant PV, 16B P swizzle): back-solve shows ~48us (~6us
// better than R8's 53.6).

#define D_MODEL 1024
#define N_HEADS 16
#define D_K     64
#define BATCH   2
#define SEQ     2048
#define M_TOT   (BATCH * SEQ)   // 4096

typedef short  s16x8 __attribute__((ext_vector_type(8)));   // 8 bf16 = 4 VGPR
typedef float  f32x4 __attribute__((ext_vector_type(4)));   // MFMA C/D frag
typedef unsigned short ushort_t;
typedef ushort_t us4 __attribute__((ext_vector_type(4)));

__device__ __forceinline__ ushort_t f2bf(float f) {
    union { float f; unsigned int u; } x; x.f = f;
    unsigned int u = x.u;
    return (ushort_t)((u + 0x7fffu + ((u >> 16) & 1u)) >> 16);  // RNE
}
__device__ __forceinline__ float bf2f(ushort_t h) {
    union { unsigned int u; float f; } x; x.u = ((unsigned int)h) << 16;
    return x.f;
}
// pack two fp32 -> u32 of two bf16 (RNE)
__device__ __forceinline__ unsigned int pack2bf(float a, float b) {
    union { __hip_bfloat162 h; unsigned int u; } x;
    x.h = __float22bfloat162_rn(float2{a, b});
    return x.u;
}

// async global->LDS, 16B per lane (lane i's lds ptr == wave base + i*16).
__device__ __forceinline__ void gload_lds16(const ushort_t* g, ushort_t* l) {
    __builtin_amdgcn_global_load_lds(
        (__attribute__((address_space(1))) void*)(ushort_t*)g,
        (__attribute__((address_space(3))) void*)l, 16, 0, 0);
}

#define WAIT_VM(n)  asm volatile("s_waitcnt vmcnt(" #n ")" ::: "memory")
#define WAIT_LGKM0  asm volatile("s_waitcnt lgkmcnt(0)" ::: "memory")
#define BARRIER     asm volatile("s_barrier" ::: "memory")

// ---------------------------------------------------------------------------
// fp32 -> bf16 conversion, all 11 inputs in one launch (blockIdx.y = tensor).
// ---------------------------------------------------------------------------
struct ConvArgs {
    const float* src[11];
    ushort_t*    dst[11];
    int          n[11];
};

__global__ __launch_bounds__(256) void convert_kernel(ConvArgs a) {
    const int t = blockIdx.y;
    const int i = (blockIdx.x * 256 + threadIdx.x) * 4;
    if (i >= a.n[t]) return;
    const float4 v = *(const float4*)(a.src[t] + i);
    us4 p;
    p[0] = f2bf(v.x); p[1] = f2bf(v.y); p[2] = f2bf(v.z); p[3] = f2bf(v.w);
    *(us4*)(a.dst[t] + i) = p;
}

// ---------------------------------------------------------------------------
// GEMM body (R8 config): BM x 128 tile, 4 waves 2x2, 2-deep DMA pipeline,
// BK=64. Per-wave DMAs per tile: BM=128 -> 8, BM=64 -> 6.
// MODE 0: fp32 row-major store   MODE 1: L2-norm -> (B,H,S,DK) bf16
// MODE 2: transpose -> (B,H,DK,S) bf16 (LDS, stride-72)
// ---------------------------------------------------------------------------
template <int BM, int MODE>
__device__ __forceinline__ void gemm_body(
    ushort_t* __restrict__ smem,
    const ushort_t* __restrict__ A,
    const ushort_t* __restrict__ W,
    const ushort_t* __restrict__ bias,
    ushort_t* __restrict__ out,
    float* __restrict__ outf,
    int bx, int by)
{
    static_assert(BM == 64 || BM == 128, "");
    constexpr int K    = 1024;
    constexpr int MF   = BM / 32;
    constexpr int BUFW = (BM + 128) * 64;
    constexpr int NIT  = K / 64;

    const int t    = threadIdx.x;
    const int wave = t >> 6;
    const int lane = t & 63;
    const int quad = lane >> 4;
    const int lc   = lane & 15;
    const int wm   = wave >> 1;
    const int wn   = wave & 1;
    const int m0   = bx * BM;
    const int n0   = by * 128;

    f32x4 acc[MF][4];
    const f32x4 zero = {0.f, 0.f, 0.f, 0.f};
#pragma unroll
    for (int i = 0; i < MF; ++i)
#pragma unroll
        for (int j = 0; j < 4; ++j) acc[i][j] = zero;

    auto stage = [&](int buf, int k0) {
        ushort_t* Ast = smem + buf * BUFW;
        ushort_t* Bst = Ast + BM * 64;
#pragma unroll
        for (int c = 0; c < MF; ++c) {
            int idx = c * 256 + t;
            int row = idx >> 3, phys = idx & 7;
            int col = (phys ^ (row & 7)) * 8;
            gload_lds16(A + (size_t)(m0 + row) * K + k0 + col, Ast + idx * 8);
        }
#pragma unroll
        for (int c = 0; c < 4; ++c) {
            int idx = c * 256 + t;
            int row = idx >> 3, phys = idx & 7;
            int col = (phys ^ (row & 7)) * 8;
            gload_lds16(W + (size_t)(n0 + row) * K + k0 + col, Bst + idx * 8);
        }
    };
    auto comp = [&](int buf) {
        ushort_t* Ast = smem + buf * BUFW;
        ushort_t* Bst = Ast + BM * 64;
#pragma unroll
        for (int ks = 0; ks < 2; ++ks) {
            const int ph = ((ks * 4 + quad) ^ (lc & 7)) * 8;
            s16x8 a[MF], b[4];
#pragma unroll
            for (int i = 0; i < MF; ++i)
                a[i] = *(const s16x8*)(Ast + (wm * (BM / 2) + i * 16 + lc) * 64 + ph);
#pragma unroll
            for (int i = 0; i < 4; ++i)
                b[i] = *(const s16x8*)(Bst + (wn * 64 + i * 16 + lc) * 64 + ph);
#pragma unroll
            for (int mf = 0; mf < MF; ++mf)
#pragma unroll
                for (int nf = 0; nf < 4; ++nf)
                    acc[mf][nf] = __builtin_amdgcn_mfma_f32_16x16x32_bf16(
                        a[mf], b[nf], acc[mf][nf], 0, 0, 0);
        }
    };

    stage(0, 0);
    stage(1, 64);
    for (int it = 0; it < NIT - 2; ++it) {
        if constexpr (BM == 128) WAIT_VM(8); else WAIT_VM(6);
        BARRIER;
        comp(it & 1);
        WAIT_LGKM0;
        BARRIER;
        stage(it & 1, (it + 2) * 64);
    }
    if constexpr (BM == 128) WAIT_VM(8); else WAIT_VM(6);
    BARRIER;
    comp((NIT - 2) & 1);
    WAIT_VM(0);
    BARRIER;
    comp((NIT - 1) & 1);

    float bv[4];
#pragma unroll
    for (int nf = 0; nf < 4; ++nf) bv[nf] = bf2f(bias[n0 + wn * 64 + nf * 16 + lc]);

    if (MODE == 0) {
#pragma unroll
        for (int mf = 0; mf < MF; ++mf)
#pragma unroll
            for (int nf = 0; nf < 4; ++nf)
#pragma unroll
                for (int r = 0; r < 4; ++r) {
                    int mg = m0 + wm * (BM / 2) + mf * 16 + quad * 4 + r;
                    int ng = n0 + wn * 64 + nf * 16 + lc;
                    outf[(size_t)mg * D_MODEL + ng] = acc[mf][nf][r] + bv[nf];
                }
    } else if (MODE == 1) {
        // wave's 64 cols == one head; row-of-64 lives in 16 lanes x 4 nf regs
#pragma unroll
        for (int mf = 0; mf < MF; ++mf)
#pragma unroll
            for (int r = 0; r < 4; ++r) {
                float ss = 0.f;
#pragma unroll
                for (int nf = 0; nf < 4; ++nf) {
                    float v = acc[mf][nf][r] + bv[nf];
                    acc[mf][nf][r] = v;
                    ss += v * v;
                }
                ss += __shfl_xor(ss, 1);
                ss += __shfl_xor(ss, 2);
                ss += __shfl_xor(ss, 4);
                ss += __shfl_xor(ss, 8);
                float inv = rsqrtf(ss + 1e-8f);
                int mg = m0 + wm * (BM / 2) + mf * 16 + quad * 4 + r;
                int b  = mg >> 11;
                int s  = mg & 2047;
#pragma unroll
                for (int nf = 0; nf < 4; ++nf) {
                    int ng = n0 + wn * 64 + nf * 16 + lc;
                    int h = ng >> 6, d = ng & 63;
                    out[(((size_t)(b * N_HEADS + h)) * SEQ + s) * D_K + d] =
                        f2bf(acc[mf][nf][r] * inv);
                }
            }
    } else {
        // MODE 2: transpose wave's 64(s)x64(d) tile through per-wave LDS
        // region [64 d][stride 72]. Block barrier first: other waves may
        // still be reading buf1 which these regions overlap.
        __syncthreads();
        ushort_t* vt = smem + wave * (64 * 72);
#pragma unroll
        for (int mf = 0; mf < 4; ++mf)
#pragma unroll
            for (int nf = 0; nf < 4; ++nf) {
                us4 p;
#pragma unroll
                for (int r = 0; r < 4; ++r) p[r] = f2bf(acc[mf][nf][r] + bv[nf]);
                *(us4*)(vt + (nf * 16 + lc) * 72 + mf * 16 + quad * 4) = p;
            }
        WAIT_LGKM0;   // wave-private region: wave-local fence suffices
#pragma unroll
        for (int r = 0; r < 8; ++r) {
            int d  = r * 8 + (lane >> 3);
            int so = (lane & 7) * 8;
            uint4 val = *(const uint4*)(vt + d * 72 + so);
            int mg = m0 + wm * 64 + so;
            int b  = mg >> 11;
            int s  = mg & 2047;
            int ng = n0 + wn * 64 + d;
            int h = ng >> 6, dh = ng & 63;
            *(uint4*)(out + (((size_t)(b * N_HEADS + h)) * D_K + dh) * SEQ + s) = val;
        }
    }
}

// fused Q/K/V projections: grid.z selects tensor (768 blocks)
__global__ __launch_bounds__(256) void qkv_kernel(
    const ushort_t* __restrict__ Qb, const ushort_t* __restrict__ Kb,
    const ushort_t* __restrict__ Vb,
    const ushort_t* __restrict__ Wq, const ushort_t* __restrict__ Wk,
    const ushort_t* __restrict__ Wv,
    const ushort_t* __restrict__ bq, const ushort_t* __restrict__ bk,
    const ushort_t* __restrict__ bv,
    ushort_t* __restrict__ qn, ushort_t* __restrict__ kn,
    ushort_t* __restrict__ vT)
{
    __shared__ __align__(16) ushort_t smem[2 * (128 + 128) * 64];  // 64 KB
    const int z = blockIdx.z;
    if (z == 0)
        gemm_body<128, 1>(smem, Qb, Wq, bq, qn, nullptr, blockIdx.x, blockIdx.y);
    else if (z == 1)
        gemm_body<128, 1>(smem, Kb, Wk, bk, kn, nullptr, blockIdx.x, blockIdx.y);
    else
        gemm_body<128, 2>(smem, Vb, Wv, bv, vT, nullptr, blockIdx.x, blockIdx.y);
}

// output projection: BM=64 -> 512 blocks
__global__ __launch_bounds__(256) void wo_kernel(
    const ushort_t* __restrict__ A, const ushort_t* __restrict__ W,
    const ushort_t* __restrict__ bias, float* __restrict__ outf)
{
    __shared__ __align__(16) ushort_t smem[2 * (64 + 128) * 64];   // 48 KB
    gemm_body<64, 0>(smem, A, W, bias, nullptr, outf, blockIdx.x, blockIdx.y);
}

// ---------------------------------------------------------------------------
// Attention (R9 config, kept): per (b,h): out = (qn kn^T)^2 v.
// Grid (x=bh 32, y=qt 16) -> 512 blocks; bh%8 pins a head to one XCD's L2.
// 128 q/block. QK^T j-partitioned -> shared P (16B XOR swizzle);
// PV quadrant-partitioned (q-half x j-half), K=32; df-panel exchange epilogue.
// ---------------------------------------------------------------------------
__global__ __launch_bounds__(256) void attn_kernel(
    const ushort_t* __restrict__ qn,
    const ushort_t* __restrict__ kn,
    const ushort_t* __restrict__ vT,
    ushort_t* __restrict__ attn_out)
{
    __shared__ __align__(16) ushort_t smem[2 * 8192];   // 32 KB (also epilogue)
    __shared__ __align__(16) ushort_t Pl[128 * 64];     // 16 KB, swizzled

    const int t    = threadIdx.x;
    const int wave = t >> 6;
    const int lane = t & 63;
    const int quad = lane >> 4;
    const int lc   = lane & 15;
    const int bh   = blockIdx.x;       // 0..31 (bh%8 -> XCD pin)
    const int qt   = blockIdx.y;       // 0..15
    const int b    = bh >> 4;
    const int h    = bh & 15;
    const int qh   = wave >> 1;        // q-half for PV
    const int jh   = wave & 1;         // j-half for PV

    const ushort_t* qb = qn + (size_t)bh * SEQ * D_K;
    const ushort_t* kb = kn + (size_t)bh * SEQ * D_K;
    const ushort_t* vb = vT + (size_t)bh * D_K * SEQ;
    const int q0 = qt * 128;

    s16x8 qf[8][2];
#pragma unroll
    for (int mf = 0; mf < 8; ++mf)
#pragma unroll
        for (int ks = 0; ks < 2; ++ks)
            qf[mf][ks] = *(const s16x8*)(qb + (size_t)(q0 + mf * 16 + lc) * D_K +
                                         ks * 32 + quad * 8);

    f32x4 oacc[4][4];
    const f32x4 zero = {0.f, 0.f, 0.f, 0.f};
#pragma unroll
    for (int mf = 0; mf < 4; ++mf)
#pragma unroll
        for (int df = 0; df < 4; ++df) oacc[mf][df] = zero;

    auto stage = [&](int buf, int j0) {
        ushort_t* kst = smem + buf * 8192;
        ushort_t* vst = kst + 4096;
#pragma unroll
        for (int c = 0; c < 2; ++c) {
            int idx = c * 256 + t;
            int row = idx >> 3, phys = idx & 7;
            int col = (phys ^ (row & 7)) * 8;
            gload_lds16(kb + (size_t)(j0 + row) * D_K + col, kst + idx * 8);
            gload_lds16(vb + (size_t)row * SEQ + j0 + col, vst + idx * 8);
        }
    };

    const int pwoff = (((wave * 2 + (quad >> 1)) ^ (lc & 7)) * 8) + (quad & 1) * 4;
    auto qk = [&](int buf) {
        ushort_t* kst = smem + buf * 8192;
        s16x8 ak[2];
#pragma unroll
        for (int ks = 0; ks < 2; ++ks)
            ak[ks] = *(const s16x8*)(kst + (wave * 16 + lc) * 64 +
                                     (((ks * 4 + quad) ^ (lc & 7)) * 8));
#pragma unroll
        for (int mf = 0; mf < 8; ++mf) {
            f32x4 st = zero;
#pragma unroll
            for (int ks = 0; ks < 2; ++ks)
                st = __builtin_amdgcn_mfma_f32_16x16x32_bf16(ak[ks], qf[mf][ks], st, 0, 0, 0);
            uint2 w;
            w.x = pack2bf(st[0] * st[0], st[1] * st[1]);
            w.y = pack2bf(st[2] * st[2], st[3] * st[3]);
            *(uint2*)(Pl + (mf * 16 + lc) * 64 + pwoff) = w;
        }
    };

    auto pv = [&](int buf) {
        ushort_t* vst = smem + buf * 8192 + 4096;
        s16x8 bvf[4];
#pragma unroll
        for (int df = 0; df < 4; ++df)
            bvf[df] = *(const s16x8*)(vst + (df * 16 + lc) * 64 +
                                      (((jh * 4 + quad) ^ (lc & 7)) * 8));
        s16x8 aa[4];
#pragma unroll
        for (int mfp = 0; mfp < 4; ++mfp) {
            const int row = qh * 64 + mfp * 16 + lc;
            aa[mfp] = *(const s16x8*)(Pl + row * 64 +
                                      (((jh * 4 + quad) ^ (lc & 7)) * 8));
        }
#pragma unroll
        for (int mfp = 0; mfp < 4; ++mfp)
#pragma unroll
            for (int df = 0; df < 4; ++df)
                oacc[mfp][df] = __builtin_amdgcn_mfma_f32_16x16x32_bf16(
                    aa[mfp], bvf[df], oacc[mfp][df], 0, 0, 0);
    };

    constexpr int NT = 32;
    stage(0, 0);
    stage(1, 64);
    for (int it = 0; it < NT; ++it) {
        if (it < NT - 1) { WAIT_VM(4); } else { WAIT_VM(0); }
        BARRIER;
        qk(it & 1);
        WAIT_LGKM0;
        BARRIER;
        pv(it & 1);
        if (it < NT - 2) {
            WAIT_LGKM0;
            BARRIER;
            stage(it & 1, (it + 2) * 64);
        } else if (it == NT - 2) {
            WAIT_LGKM0;
            BARRIER;
        }
    }

    __syncthreads();
    float* red = (float*)smem;
    {
        const int reg = qh * 2 + (jh ^ 1);
        const int dfb = (jh ^ 1) * 2;
#pragma unroll
        for (int mfp = 0; mfp < 4; ++mfp)
#pragma unroll
            for (int dd = 0; dd < 2; ++dd)
#pragma unroll
                for (int r = 0; r < 4; ++r)
                    red[reg * 2048 + (mfp * 16 + quad * 4 + r) * 32 + dd * 16 + lc] =
                        oacc[mfp][dfb + dd][r];
    }
    __syncthreads();
    {
        const int reg = qh * 2 + jh;
        const int dfb = jh * 2;
#pragma unroll
        for (int mfp = 0; mfp < 4; ++mfp)
#pragma unroll
            for (int dd = 0; dd < 2; ++dd)
#pragma unroll
                for (int r = 0; r < 4; ++r) {
                    float v = oacc[mfp][dfb + dd][r] +
                              red[reg * 2048 + (mfp * 16 + quad * 4 + r) * 32 + dd * 16 + lc];
                    int s = q0 + qh * 64 + mfp * 16 + quad * 4 + r;
                    int d = (dfb + dd) * 16 + lc;
                    attn_out[((size_t)(b * SEQ + s)) * D_MODEL + h * D_K + d] = f2bf(v);
                }
    }
}

extern "C" void kernel_launch(void* const* d_in, const int* in_sizes, int n_in,
                              void* d_out, int out_size, void* d_ws, size_t ws_size,
                              hipStream_t stream)
{
    const float* Qf   = (const float*)d_in[0];
    const float* Kf   = (const float*)d_in[1];
    const float* Vf   = (const float*)d_in[2];
    const float* Wqf  = (const float*)d_in[3];
    const float* Wqbf = (const float*)d_in[4];
    const float* Wkf  = (const float*)d_in[5];
    const float* Wkbf = (const float*)d_in[6];
    const float* Wvf  = (const float*)d_in[7];
    const float* Wvbf = (const float*)d_in[8];
    const float* Wof  = (const float*)d_in[9];
    const float* Wobf = (const float*)d_in[10];

    const size_t NM = (size_t)M_TOT * D_MODEL;
    const size_t NW = (size_t)D_MODEL * D_MODEL;
    const size_t NB = D_MODEL;

    ushort_t* p = (ushort_t*)d_ws;
    ushort_t* Qb  = p;  p += NM;
    ushort_t* Kb  = p;  p += NM;
    ushort_t* Vb  = p;  p += NM;
    ushort_t* Wq  = p;  p += NW;
    ushort_t* Wk  = p;  p += NW;
    ushort_t* Wv  = p;  p += NW;
    ushort_t* Wo  = p;  p += NW;
    ushort_t* bq  = p;  p += NB;
    ushort_t* bk  = p;  p += NB;
    ushort_t* bvv = p;  p += NB;
    ushort_t* bo  = p;  p += NB;
    ushort_t* qn  = p;  p += NM;   // (B,H,S,DK)
    ushort_t* kn  = p;  p += NM;   // (B,H,S,DK)
    ushort_t* vT  = p;  p += NM;   // (B,H,DK,S)
    ushort_t* ao  = p;  p += NM;   // (B,S,D)

    ConvArgs ca;
    ca.src[0] = Qf;   ca.dst[0] = Qb;  ca.n[0] = (int)NM;
    ca.src[1] = Kf;   ca.dst[1] = Kb;  ca.n[1] = (int)NM;
    ca.src[2] = Vf;   ca.dst[2] = Vb;  ca.n[2] = (int)NM;
    ca.src[3] = Wqf;  ca.dst[3] = Wq;  ca.n[3] = (int)NW;
    ca.src[4] = Wkf;  ca.dst[4] = Wk;  ca.n[4] = (int)NW;
    ca.src[5] = Wvf;  ca.dst[5] = Wv;  ca.n[5] = (int)NW;
    ca.src[6] = Wof;  ca.dst[6] = Wo;  ca.n[6] = (int)NW;
    ca.src[7] = Wqbf; ca.dst[7] = bq;  ca.n[7] = (int)NB;
    ca.src[8] = Wkbf; ca.dst[8] = bk;  ca.n[8] = (int)NB;
    ca.src[9] = Wvbf; ca.dst[9] = bvv; ca.n[9] = (int)NB;
    ca.src[10] = Wobf; ca.dst[10] = bo; ca.n[10] = (int)NB;

    dim3 blk(256);
    convert_kernel<<<dim3((unsigned)(NM / (256 * 4)), 11), blk, 0, stream>>>(ca);

    qkv_kernel<<<dim3(M_TOT / 128, D_MODEL / 128, 3), blk, 0, stream>>>(
        Qb, Kb, Vb, Wq, Wk, Wv, bq, bk, bvv, qn, kn, vT);
    attn_kernel<<<dim3(BATCH * N_HEADS, SEQ / 128), blk, 0, stream>>>(qn, kn, vT, ao);
    wo_kernel<<<dim3(M_TOT / 64, D_MODEL / 128), blk, 0, stream>>>(
        ao, Wo, bo, (float*)d_out);
}

// Round 11
// 228.135 us; speedup vs baseline: 1.1109x; 1.0738x over previous
//
#include <hip/hip_runtime.h>
#include <hip/hip_bf16.h>

// Problem: B=2, S=2048, D_MODEL=1024, H=16, DK=64.
// out = ((l2norm(Q Wq^T) l2norm(K Wk^T)^T)^2 (V Wv^T)) Wo^T   (per head)
// fp32 in/out; internally bf16 MFMA with fp32 accumulation.
//
// Round 11: restore FULL R8 (best known: 225.7us).
//  - attn back to R8: PV q-slice partitioned over full j (V dup in LDS is
//    the cheap direction), full-128B-line output stores. R9/R10's quadrant
//    PV split output lines between waves -> write-allocate RMW (WRITE
//    8.2->79.7 MB, FETCH +16 MB) and 53.6->76us regression.
//  - gemm stays R8 (BK=64, 2-deep vmcnt pipeline).
//  - NEW (one clean change): qkv/wo grids swapped so blockIdx.x = N-panel
//    -> id%8 pins each W-panel to one XCD L2 (R6-verified mechanism);
//    B-tile DMAs drain at L2 latency instead of L3/HBM.

#define D_MODEL 1024
#define N_HEADS 16
#define D_K     64
#define BATCH   2
#define SEQ     2048
#define M_TOT   (BATCH * SEQ)   // 4096

typedef short  s16x8 __attribute__((ext_vector_type(8)));   // 8 bf16 = 4 VGPR
typedef float  f32x4 __attribute__((ext_vector_type(4)));   // MFMA C/D frag
typedef unsigned short ushort_t;
typedef ushort_t us4 __attribute__((ext_vector_type(4)));

__device__ __forceinline__ ushort_t f2bf(float f) {
    union { float f; unsigned int u; } x; x.f = f;
    unsigned int u = x.u;
    return (ushort_t)((u + 0x7fffu + ((u >> 16) & 1u)) >> 16);  // RNE
}
__device__ __forceinline__ float bf2f(ushort_t h) {
    union { unsigned int u; float f; } x; x.u = ((unsigned int)h) << 16;
    return x.f;
}
// pack two fp32 -> u32 of two bf16 (RNE)
__device__ __forceinline__ unsigned int pack2bf(float a, float b) {
    union { __hip_bfloat162 h; unsigned int u; } x;
    x.h = __float22bfloat162_rn(float2{a, b});
    return x.u;
}

// async global->LDS, 16B per lane (lane i's lds ptr == wave base + i*16).
__device__ __forceinline__ void gload_lds16(const ushort_t* g, ushort_t* l) {
    __builtin_amdgcn_global_load_lds(
        (__attribute__((address_space(1))) void*)(ushort_t*)g,
        (__attribute__((address_space(3))) void*)l, 16, 0, 0);
}

#define WAIT_VM(n)  asm volatile("s_waitcnt vmcnt(" #n ")" ::: "memory")
#define WAIT_LGKM0  asm volatile("s_waitcnt lgkmcnt(0)" ::: "memory")
#define BARRIER     asm volatile("s_barrier" ::: "memory")

// ---------------------------------------------------------------------------
// fp32 -> bf16 conversion, all 11 inputs in one launch (blockIdx.y = tensor).
// ---------------------------------------------------------------------------
struct ConvArgs {
    const float* src[11];
    ushort_t*    dst[11];
    int          n[11];
};

__global__ __launch_bounds__(256) void convert_kernel(ConvArgs a) {
    const int t = blockIdx.y;
    const int i = (blockIdx.x * 256 + threadIdx.x) * 4;
    if (i >= a.n[t]) return;
    const float4 v = *(const float4*)(a.src[t] + i);
    us4 p;
    p[0] = f2bf(v.x); p[1] = f2bf(v.y); p[2] = f2bf(v.z); p[3] = f2bf(v.w);
    *(us4*)(a.dst[t] + i) = p;
}

// ---------------------------------------------------------------------------
// GEMM body (R8 config): BM x 128 tile, 4 waves 2x2, 2-deep DMA pipeline,
// BK=64. Per-wave DMAs per tile: BM=128 -> 8, BM=64 -> 6.
// MODE 0: fp32 row-major store   MODE 1: L2-norm -> (B,H,S,DK) bf16
// MODE 2: transpose -> (B,H,DK,S) bf16 (LDS, stride-72)
// ---------------------------------------------------------------------------
template <int BM, int MODE>
__device__ __forceinline__ void gemm_body(
    ushort_t* __restrict__ smem,
    const ushort_t* __restrict__ A,
    const ushort_t* __restrict__ W,
    const ushort_t* __restrict__ bias,
    ushort_t* __restrict__ out,
    float* __restrict__ outf,
    int bx, int by)
{
    static_assert(BM == 64 || BM == 128, "");
    constexpr int K    = 1024;
    constexpr int MF   = BM / 32;
    constexpr int BUFW = (BM + 128) * 64;
    constexpr int NIT  = K / 64;

    const int t    = threadIdx.x;
    const int wave = t >> 6;
    const int lane = t & 63;
    const int quad = lane >> 4;
    const int lc   = lane & 15;
    const int wm   = wave >> 1;
    const int wn   = wave & 1;
    const int m0   = bx * BM;
    const int n0   = by * 128;

    f32x4 acc[MF][4];
    const f32x4 zero = {0.f, 0.f, 0.f, 0.f};
#pragma unroll
    for (int i = 0; i < MF; ++i)
#pragma unroll
        for (int j = 0; j < 4; ++j) acc[i][j] = zero;

    auto stage = [&](int buf, int k0) {
        ushort_t* Ast = smem + buf * BUFW;
        ushort_t* Bst = Ast + BM * 64;
#pragma unroll
        for (int c = 0; c < MF; ++c) {
            int idx = c * 256 + t;
            int row = idx >> 3, phys = idx & 7;
            int col = (phys ^ (row & 7)) * 8;
            gload_lds16(A + (size_t)(m0 + row) * K + k0 + col, Ast + idx * 8);
        }
#pragma unroll
        for (int c = 0; c < 4; ++c) {
            int idx = c * 256 + t;
            int row = idx >> 3, phys = idx & 7;
            int col = (phys ^ (row & 7)) * 8;
            gload_lds16(W + (size_t)(n0 + row) * K + k0 + col, Bst + idx * 8);
        }
    };
    auto comp = [&](int buf) {
        ushort_t* Ast = smem + buf * BUFW;
        ushort_t* Bst = Ast + BM * 64;
#pragma unroll
        for (int ks = 0; ks < 2; ++ks) {
            const int ph = ((ks * 4 + quad) ^ (lc & 7)) * 8;
            s16x8 a[MF], b[4];
#pragma unroll
            for (int i = 0; i < MF; ++i)
                a[i] = *(const s16x8*)(Ast + (wm * (BM / 2) + i * 16 + lc) * 64 + ph);
#pragma unroll
            for (int i = 0; i < 4; ++i)
                b[i] = *(const s16x8*)(Bst + (wn * 64 + i * 16 + lc) * 64 + ph);
#pragma unroll
            for (int mf = 0; mf < MF; ++mf)
#pragma unroll
                for (int nf = 0; nf < 4; ++nf)
                    acc[mf][nf] = __builtin_amdgcn_mfma_f32_16x16x32_bf16(
                        a[mf], b[nf], acc[mf][nf], 0, 0, 0);
        }
    };

    stage(0, 0);
    stage(1, 64);
    for (int it = 0; it < NIT - 2; ++it) {
        if constexpr (BM == 128) WAIT_VM(8); else WAIT_VM(6);
        BARRIER;
        comp(it & 1);
        WAIT_LGKM0;
        BARRIER;
        stage(it & 1, (it + 2) * 64);
    }
    if constexpr (BM == 128) WAIT_VM(8); else WAIT_VM(6);
    BARRIER;
    comp((NIT - 2) & 1);
    WAIT_VM(0);
    BARRIER;
    comp((NIT - 1) & 1);

    float bv[4];
#pragma unroll
    for (int nf = 0; nf < 4; ++nf) bv[nf] = bf2f(bias[n0 + wn * 64 + nf * 16 + lc]);

    if (MODE == 0) {
#pragma unroll
        for (int mf = 0; mf < MF; ++mf)
#pragma unroll
            for (int nf = 0; nf < 4; ++nf)
#pragma unroll
                for (int r = 0; r < 4; ++r) {
                    int mg = m0 + wm * (BM / 2) + mf * 16 + quad * 4 + r;
                    int ng = n0 + wn * 64 + nf * 16 + lc;
                    outf[(size_t)mg * D_MODEL + ng] = acc[mf][nf][r] + bv[nf];
                }
    } else if (MODE == 1) {
        // wave's 64 cols == one head; row-of-64 lives in 16 lanes x 4 nf regs
#pragma unroll
        for (int mf = 0; mf < MF; ++mf)
#pragma unroll
            for (int r = 0; r < 4; ++r) {
                float ss = 0.f;
#pragma unroll
                for (int nf = 0; nf < 4; ++nf) {
                    float v = acc[mf][nf][r] + bv[nf];
                    acc[mf][nf][r] = v;
                    ss += v * v;
                }
                ss += __shfl_xor(ss, 1);
                ss += __shfl_xor(ss, 2);
                ss += __shfl_xor(ss, 4);
                ss += __shfl_xor(ss, 8);
                float inv = rsqrtf(ss + 1e-8f);
                int mg = m0 + wm * (BM / 2) + mf * 16 + quad * 4 + r;
                int b  = mg >> 11;
                int s  = mg & 2047;
#pragma unroll
                for (int nf = 0; nf < 4; ++nf) {
                    int ng = n0 + wn * 64 + nf * 16 + lc;
                    int h = ng >> 6, d = ng & 63;
                    out[(((size_t)(b * N_HEADS + h)) * SEQ + s) * D_K + d] =
                        f2bf(acc[mf][nf][r] * inv);
                }
            }
    } else {
        // MODE 2: transpose wave's 64(s)x64(d) tile through per-wave LDS
        // region [64 d][stride 72]. Block barrier first: other waves may
        // still be reading buf1 which these regions overlap.
        __syncthreads();
        ushort_t* vt = smem + wave * (64 * 72);
#pragma unroll
        for (int mf = 0; mf < 4; ++mf)
#pragma unroll
            for (int nf = 0; nf < 4; ++nf) {
                us4 p;
#pragma unroll
                for (int r = 0; r < 4; ++r) p[r] = f2bf(acc[mf][nf][r] + bv[nf]);
                *(us4*)(vt + (nf * 16 + lc) * 72 + mf * 16 + quad * 4) = p;
            }
        WAIT_LGKM0;   // wave-private region: wave-local fence suffices
#pragma unroll
        for (int r = 0; r < 8; ++r) {
            int d  = r * 8 + (lane >> 3);
            int so = (lane & 7) * 8;
            uint4 val = *(const uint4*)(vt + d * 72 + so);
            int mg = m0 + wm * 64 + so;
            int b  = mg >> 11;
            int s  = mg & 2047;
            int ng = n0 + wn * 64 + d;
            int h = ng >> 6, dh = ng & 63;
            *(uint4*)(out + (((size_t)(b * N_HEADS + h)) * D_K + dh) * SEQ + s) = val;
        }
    }
}

// fused Q/K/V projections. Grid (x=N-panel 8, y=M 32, z=3): id%8 == N-panel
// -> each W-panel pinned to one XCD's L2.
__global__ __launch_bounds__(256) void qkv_kernel(
    const ushort_t* __restrict__ Qb, const ushort_t* __restrict__ Kb,
    const ushort_t* __restrict__ Vb,
    const ushort_t* __restrict__ Wq, const ushort_t* __restrict__ Wk,
    const ushort_t* __restrict__ Wv,
    const ushort_t* __restrict__ bq, const ushort_t* __restrict__ bk,
    const ushort_t* __restrict__ bv,
    ushort_t* __restrict__ qn, ushort_t* __restrict__ kn,
    ushort_t* __restrict__ vT)
{
    __shared__ __align__(16) ushort_t smem[2 * (128 + 128) * 64];  // 64 KB
    const int z = blockIdx.z;
    if (z == 0)
        gemm_body<128, 1>(smem, Qb, Wq, bq, qn, nullptr, blockIdx.y, blockIdx.x);
    else if (z == 1)
        gemm_body<128, 1>(smem, Kb, Wk, bk, kn, nullptr, blockIdx.y, blockIdx.x);
    else
        gemm_body<128, 2>(smem, Vb, Wv, bv, vT, nullptr, blockIdx.y, blockIdx.x);
}

// output projection: BM=64, grid (x=N 8, y=M 64) -> W-panel XCD pin
__global__ __launch_bounds__(256) void wo_kernel(
    const ushort_t* __restrict__ A, const ushort_t* __restrict__ W,
    const ushort_t* __restrict__ bias, float* __restrict__ outf)
{
    __shared__ __align__(16) ushort_t smem[2 * (64 + 128) * 64];   // 48 KB
    gemm_body<64, 0>(smem, A, W, bias, nullptr, outf, blockIdx.y, blockIdx.x);
}

// ---------------------------------------------------------------------------
// Attention (R8 config restored): per (b,h): out = (qn kn^T)^2 v.
// Grid (x=bh 32, y=qt 16) -> 512 blocks; bh%8 pins a head to one XCD's L2.
// 128 q/block. QK^T: wave w owns j-slice [w*16,+16) -> shared P[128q][64j]
// (8B XOR swizzle). PV: wave w owns q-slice [w*32,+32), K=32 over full 64 j
// (aa assembled from 2x uint2). Epilogue: full-line stores per wave.
// ---------------------------------------------------------------------------
__global__ __launch_bounds__(256) void attn_kernel(
    const ushort_t* __restrict__ qn,
    const ushort_t* __restrict__ kn,
    const ushort_t* __restrict__ vT,
    ushort_t* __restrict__ attn_out)
{
    // staging buf i at smem+i*8192: kst [64 j][64 dk] + vst [64 d][64 j]
    __shared__ __align__(16) ushort_t smem[2 * 8192];   // 32 KB
    __shared__ __align__(16) ushort_t Pl[128 * 64];     // 16 KB, swizzled

    const int t    = threadIdx.x;
    const int wave = t >> 6;
    const int lane = t & 63;
    const int quad = lane >> 4;
    const int lc   = lane & 15;
    const int bh   = blockIdx.x;       // 0..31 (bh%8 -> XCD pin)
    const int qt   = blockIdx.y;       // 0..15
    const int b    = bh >> 4;
    const int h    = bh & 15;

    const ushort_t* qb = qn + (size_t)bh * SEQ * D_K;
    const ushort_t* kb = kn + (size_t)bh * SEQ * D_K;
    const ushort_t* vb = vT + (size_t)bh * D_K * SEQ;
    const int q0 = qt * 128;

    // Q B-frags for all 8 q-tiles of this block, reused over 32 k-tiles
    s16x8 qf[8][2];
#pragma unroll
    for (int mf = 0; mf < 8; ++mf)
#pragma unroll
        for (int ks = 0; ks < 2; ++ks)
            qf[mf][ks] = *(const s16x8*)(qb + (size_t)(q0 + mf * 16 + lc) * D_K +
                                         ks * 32 + quad * 8);

    f32x4 oacc[2][4];                  // wave's q-slice [32 q][64 d]
    const f32x4 zero = {0.f, 0.f, 0.f, 0.f};
#pragma unroll
    for (int mf = 0; mf < 2; ++mf)
#pragma unroll
        for (int df = 0; df < 4; ++df) oacc[mf][df] = zero;

    auto stage = [&](int buf, int j0) {
        ushort_t* kst = smem + buf * 8192;
        ushort_t* vst = kst + 4096;
#pragma unroll
        for (int c = 0; c < 2; ++c) {
            int idx = c * 256 + t;
            int row = idx >> 3, phys = idx & 7;
            int col = (phys ^ (row & 7)) * 8;
            gload_lds16(kb + (size_t)(j0 + row) * D_K + col, kst + idx * 8);
            gload_lds16(vb + (size_t)row * SEQ + j0 + col, vst + idx * 8);
        }
    };

    // QK^T phase: wave's 16-j slice vs all 128 q -> P
    auto qk = [&](int buf) {
        ushort_t* kst = smem + buf * 8192;
        s16x8 ak[2];
#pragma unroll
        for (int ks = 0; ks < 2; ++ks)
            ak[ks] = *(const s16x8*)(kst + (wave * 16 + lc) * 64 +
                                     (((ks * 4 + quad) ^ (lc & 7)) * 8));
        const int log8 = wave * 4 + quad;   // 8B chunk of wave's j in a P row
#pragma unroll
        for (int mf = 0; mf < 8; ++mf) {
            f32x4 st = zero;   // S^T tile: lane = [j=quad*4+r][q=lc]
#pragma unroll
            for (int ks = 0; ks < 2; ++ks)
                st = __builtin_amdgcn_mfma_f32_16x16x32_bf16(ak[ks], qf[mf][ks], st, 0, 0, 0);
            uint2 w;
            w.x = pack2bf(st[0] * st[0], st[1] * st[1]);
            w.y = pack2bf(st[2] * st[2], st[3] * st[3]);
            const int row = mf * 16 + lc;
            *(uint2*)(Pl + row * 64 + (log8 ^ lc) * 4) = w;
        }
    };

    // PV phase: wave's 32-q slice, K=32 over the full 64-j tile
    auto pv = [&](int buf) {
        ushort_t* vst = smem + buf * 8192 + 4096;
        s16x8 bvf[4][2];
#pragma unroll
        for (int df = 0; df < 4; ++df)
#pragma unroll
            for (int ks = 0; ks < 2; ++ks)
                bvf[df][ks] = *(const s16x8*)(vst + (df * 16 + lc) * 64 +
                                              (((ks * 4 + quad) ^ (lc & 7)) * 8));
        s16x8 aa[2][2];
#pragma unroll
        for (int mfp = 0; mfp < 2; ++mfp)
#pragma unroll
            for (int ks = 0; ks < 2; ++ks) {
                const int row = wave * 32 + mfp * 16 + lc;
                const int l0  = ks * 8 + quad * 2;
                uint2 lo = *(const uint2*)(Pl + row * 64 + ((l0 ^ lc) * 4));
                uint2 hi = *(const uint2*)(Pl + row * 64 + (((l0 + 1) ^ lc) * 4));
                union { unsigned int u[4]; s16x8 v; } m;
                m.u[0] = lo.x; m.u[1] = lo.y; m.u[2] = hi.x; m.u[3] = hi.y;
                aa[mfp][ks] = m.v;
            }
#pragma unroll
        for (int mfp = 0; mfp < 2; ++mfp)
#pragma unroll
            for (int df = 0; df < 4; ++df)
#pragma unroll
                for (int ks = 0; ks < 2; ++ks)
                    oacc[mfp][df] = __builtin_amdgcn_mfma_f32_16x16x32_bf16(
                        aa[mfp][ks], bvf[df][ks], oacc[mfp][df], 0, 0, 0);
    };

    constexpr int NT = 32;
    stage(0, 0);
    stage(1, 64);
    for (int it = 0; it < NT; ++it) {
        if (it < NT - 1) { WAIT_VM(4); } else { WAIT_VM(0); }
        BARRIER;                       // k/v tile `it` landed everywhere
        qk(it & 1);
        WAIT_LGKM0;
        BARRIER;                       // P complete; kst reads done
        pv(it & 1);
        if (it < NT - 2) {
            WAIT_LGKM0;
            BARRIER;                   // vst + P reads done -> buf reusable
            stage(it & 1, (it + 2) * 64);
        } else if (it == NT - 2) {
            WAIT_LGKM0;
            BARRIER;                   // protect P for the last qk()
        }
    }

    // store wave's [32 q][64 d] to (B,S,D) head-interleaved bf16.
    // Each wave writes FULL 128B lines (all 64 d per s) -> clean
    // write-combining, no write-allocate RMW (R9/R10 lesson).
#pragma unroll
    for (int mfp = 0; mfp < 2; ++mfp)
#pragma unroll
        for (int df = 0; df < 4; ++df)
#pragma unroll
            for (int r = 0; r < 4; ++r) {
                int s = q0 + wave * 32 + mfp * 16 + quad * 4 + r;
                int d = df * 16 + lc;
                attn_out[((size_t)(b * SEQ + s)) * D_MODEL + h * D_K + d] =
                    f2bf(oacc[mfp][df][r]);
            }
}

extern "C" void kernel_launch(void* const* d_in, const int* in_sizes, int n_in,
                              void* d_out, int out_size, void* d_ws, size_t ws_size,
                              hipStream_t stream)
{
    const float* Qf   = (const float*)d_in[0];
    const float* Kf   = (const float*)d_in[1];
    const float* Vf   = (const float*)d_in[2];
    const float* Wqf  = (const float*)d_in[3];
    const float* Wqbf = (const float*)d_in[4];
    const float* Wkf  = (const float*)d_in[5];
    const float* Wkbf = (const float*)d_in[6];
    const float* Wvf  = (const float*)d_in[7];
    const float* Wvbf = (const float*)d_in[8];
    const float* Wof  = (const float*)d_in[9];
    const float* Wobf = (const float*)d_in[10];

    const size_t NM = (size_t)M_TOT * D_MODEL;
    const size_t NW = (size_t)D_MODEL * D_MODEL;
    const size_t NB = D_MODEL;

    ushort_t* p = (ushort_t*)d_ws;
    ushort_t* Qb  = p;  p += NM;
    ushort_t* Kb  = p;  p += NM;
    ushort_t* Vb  = p;  p += NM;
    ushort_t* Wq  = p;  p += NW;
    ushort_t* Wk  = p;  p += NW;
    ushort_t* Wv  = p;  p += NW;
    ushort_t* Wo  = p;  p += NW;
    ushort_t* bq  = p;  p += NB;
    ushort_t* bk  = p;  p += NB;
    ushort_t* bvv = p;  p += NB;
    ushort_t* bo  = p;  p += NB;
    ushort_t* qn  = p;  p += NM;   // (B,H,S,DK)
    ushort_t* kn  = p;  p += NM;   // (B,H,S,DK)
    ushort_t* vT  = p;  p += NM;   // (B,H,DK,S)
    ushort_t* ao  = p;  p += NM;   // (B,S,D)

    ConvArgs ca;
    ca.src[0] = Qf;   ca.dst[0] = Qb;  ca.n[0] = (int)NM;
    ca.src[1] = Kf;   ca.dst[1] = Kb;  ca.n[1] = (int)NM;
    ca.src[2] = Vf;   ca.dst[2] = Vb;  ca.n[2] = (int)NM;
    ca.src[3] = Wqf;  ca.dst[3] = Wq;  ca.n[3] = (int)NW;
    ca.src[4] = Wkf;  ca.dst[4] = Wk;  ca.n[4] = (int)NW;
    ca.src[5] = Wvf;  ca.dst[5] = Wv;  ca.n[5] = (int)NW;
    ca.src[6] = Wof;  ca.dst[6] = Wo;  ca.n[6] = (int)NW;
    ca.src[7] = Wqbf; ca.dst[7] = bq;  ca.n[7] = (int)NB;
    ca.src[8] = Wkbf; ca.dst[8] = bk;  ca.n[8] = (int)NB;
    ca.src[9] = Wvbf; ca.dst[9] = bvv; ca.n[9] = (int)NB;
    ca.src[10] = Wobf; ca.dst[10] = bo; ca.n[10] = (int)NB;

    dim3 blk(256);
    convert_kernel<<<dim3((unsigned)(NM / (256 * 4)), 11), blk, 0, stream>>>(ca);

    qkv_kernel<<<dim3(D_MODEL / 128, M_TOT / 128, 3), blk, 0, stream>>>(
        Qb, Kb, Vb, Wq, Wk, Wv, bq, bk, bvv, qn, kn, vT);
    attn_kernel<<<dim3(BATCH * N_HEADS, SEQ / 128), blk, 0, stream>>>(qn, kn, vT, ao);
    wo_kernel<<<dim3(D_MODEL / 128, M_TOT / 64), blk, 0, stream>>>(
        ao, Wo, bo, (float*)d_out);
}

// Round 12
// 227.105 us; speedup vs baseline: 1.1159x; 1.0045x over previous
//
#include <hip/hip_runtime.h>
#include <hip/hip_bf16.h>

// Problem: B=2, S=2048, D_MODEL=1024, H=16, DK=64.
// out = ((l2norm(Q Wq^T) l2norm(K Wk^T)^T)^2 (V Wv^T)) Wo^T   (per head)
// fp32 in/out; internally bf16 MFMA with fp32 accumulation.
//
// Round 12: EXACT R8 restore (best known: 225.7us). R11's W-panel XCD pin
// (x=N) spread the big A operand across all XCDs: FETCH 37->101.6 MB,
// qkv 50->92us. Lesson: pin the operand with the largest footprint x reuse
// (A M-stripes), which is what R8's x=M mapping already did.
// Verified-best components:
//  - gemm: BM=128/64, BK=64, 2-deep vmcnt(8/6) DMA pipeline, grid x=M y=N
//  - attn: 128q/block, j-sliced QK^T -> shared P (8B XOR swizzle, 0
//    conflicts), q-sliced K=32 PV, full-128B-line output stores
//    (WRITE=8.2 MB exact, no RMW)

#define D_MODEL 1024
#define N_HEADS 16
#define D_K     64
#define BATCH   2
#define SEQ     2048
#define M_TOT   (BATCH * SEQ)   // 4096

typedef short  s16x8 __attribute__((ext_vector_type(8)));   // 8 bf16 = 4 VGPR
typedef float  f32x4 __attribute__((ext_vector_type(4)));   // MFMA C/D frag
typedef unsigned short ushort_t;
typedef ushort_t us4 __attribute__((ext_vector_type(4)));

__device__ __forceinline__ ushort_t f2bf(float f) {
    union { float f; unsigned int u; } x; x.f = f;
    unsigned int u = x.u;
    return (ushort_t)((u + 0x7fffu + ((u >> 16) & 1u)) >> 16);  // RNE
}
__device__ __forceinline__ float bf2f(ushort_t h) {
    union { unsigned int u; float f; } x; x.u = ((unsigned int)h) << 16;
    return x.f;
}
// pack two fp32 -> u32 of two bf16 (RNE)
__device__ __forceinline__ unsigned int pack2bf(float a, float b) {
    union { __hip_bfloat162 h; unsigned int u; } x;
    x.h = __float22bfloat162_rn(float2{a, b});
    return x.u;
}

// async global->LDS, 16B per lane (lane i's lds ptr == wave base + i*16).
__device__ __forceinline__ void gload_lds16(const ushort_t* g, ushort_t* l) {
    __builtin_amdgcn_global_load_lds(
        (__attribute__((address_space(1))) void*)(ushort_t*)g,
        (__attribute__((address_space(3))) void*)l, 16, 0, 0);
}

#define WAIT_VM(n)  asm volatile("s_waitcnt vmcnt(" #n ")" ::: "memory")
#define WAIT_LGKM0  asm volatile("s_waitcnt lgkmcnt(0)" ::: "memory")
#define BARRIER     asm volatile("s_barrier" ::: "memory")

// ---------------------------------------------------------------------------
// fp32 -> bf16 conversion, all 11 inputs in one launch (blockIdx.y = tensor).
// ---------------------------------------------------------------------------
struct ConvArgs {
    const float* src[11];
    ushort_t*    dst[11];
    int          n[11];
};

__global__ __launch_bounds__(256) void convert_kernel(ConvArgs a) {
    const int t = blockIdx.y;
    const int i = (blockIdx.x * 256 + threadIdx.x) * 4;
    if (i >= a.n[t]) return;
    const float4 v = *(const float4*)(a.src[t] + i);
    us4 p;
    p[0] = f2bf(v.x); p[1] = f2bf(v.y); p[2] = f2bf(v.z); p[3] = f2bf(v.w);
    *(us4*)(a.dst[t] + i) = p;
}

// ---------------------------------------------------------------------------
// GEMM body (R8 config): BM x 128 tile, 4 waves 2x2, 2-deep DMA pipeline,
// BK=64. Per-wave DMAs per tile: BM=128 -> 8, BM=64 -> 6.
// MODE 0: fp32 row-major store   MODE 1: L2-norm -> (B,H,S,DK) bf16
// MODE 2: transpose -> (B,H,DK,S) bf16 (LDS, stride-72)
// ---------------------------------------------------------------------------
template <int BM, int MODE>
__device__ __forceinline__ void gemm_body(
    ushort_t* __restrict__ smem,
    const ushort_t* __restrict__ A,
    const ushort_t* __restrict__ W,
    const ushort_t* __restrict__ bias,
    ushort_t* __restrict__ out,
    float* __restrict__ outf,
    int bx, int by)
{
    static_assert(BM == 64 || BM == 128, "");
    constexpr int K    = 1024;
    constexpr int MF   = BM / 32;
    constexpr int BUFW = (BM + 128) * 64;
    constexpr int NIT  = K / 64;

    const int t    = threadIdx.x;
    const int wave = t >> 6;
    const int lane = t & 63;
    const int quad = lane >> 4;
    const int lc   = lane & 15;
    const int wm   = wave >> 1;
    const int wn   = wave & 1;
    const int m0   = bx * BM;
    const int n0   = by * 128;

    f32x4 acc[MF][4];
    const f32x4 zero = {0.f, 0.f, 0.f, 0.f};
#pragma unroll
    for (int i = 0; i < MF; ++i)
#pragma unroll
        for (int j = 0; j < 4; ++j) acc[i][j] = zero;

    auto stage = [&](int buf, int k0) {
        ushort_t* Ast = smem + buf * BUFW;
        ushort_t* Bst = Ast + BM * 64;
#pragma unroll
        for (int c = 0; c < MF; ++c) {
            int idx = c * 256 + t;
            int row = idx >> 3, phys = idx & 7;
            int col = (phys ^ (row & 7)) * 8;
            gload_lds16(A + (size_t)(m0 + row) * K + k0 + col, Ast + idx * 8);
        }
#pragma unroll
        for (int c = 0; c < 4; ++c) {
            int idx = c * 256 + t;
            int row = idx >> 3, phys = idx & 7;
            int col = (phys ^ (row & 7)) * 8;
            gload_lds16(W + (size_t)(n0 + row) * K + k0 + col, Bst + idx * 8);
        }
    };
    auto comp = [&](int buf) {
        ushort_t* Ast = smem + buf * BUFW;
        ushort_t* Bst = Ast + BM * 64;
#pragma unroll
        for (int ks = 0; ks < 2; ++ks) {
            const int ph = ((ks * 4 + quad) ^ (lc & 7)) * 8;
            s16x8 a[MF], b[4];
#pragma unroll
            for (int i = 0; i < MF; ++i)
                a[i] = *(const s16x8*)(Ast + (wm * (BM / 2) + i * 16 + lc) * 64 + ph);
#pragma unroll
            for (int i = 0; i < 4; ++i)
                b[i] = *(const s16x8*)(Bst + (wn * 64 + i * 16 + lc) * 64 + ph);
#pragma unroll
            for (int mf = 0; mf < MF; ++mf)
#pragma unroll
                for (int nf = 0; nf < 4; ++nf)
                    acc[mf][nf] = __builtin_amdgcn_mfma_f32_16x16x32_bf16(
                        a[mf], b[nf], acc[mf][nf], 0, 0, 0);
        }
    };

    stage(0, 0);
    stage(1, 64);
    for (int it = 0; it < NIT - 2; ++it) {
        if constexpr (BM == 128) WAIT_VM(8); else WAIT_VM(6);
        BARRIER;
        comp(it & 1);
        WAIT_LGKM0;
        BARRIER;
        stage(it & 1, (it + 2) * 64);
    }
    if constexpr (BM == 128) WAIT_VM(8); else WAIT_VM(6);
    BARRIER;
    comp((NIT - 2) & 1);
    WAIT_VM(0);
    BARRIER;
    comp((NIT - 1) & 1);

    float bv[4];
#pragma unroll
    for (int nf = 0; nf < 4; ++nf) bv[nf] = bf2f(bias[n0 + wn * 64 + nf * 16 + lc]);

    if (MODE == 0) {
#pragma unroll
        for (int mf = 0; mf < MF; ++mf)
#pragma unroll
            for (int nf = 0; nf < 4; ++nf)
#pragma unroll
                for (int r = 0; r < 4; ++r) {
                    int mg = m0 + wm * (BM / 2) + mf * 16 + quad * 4 + r;
                    int ng = n0 + wn * 64 + nf * 16 + lc;
                    outf[(size_t)mg * D_MODEL + ng] = acc[mf][nf][r] + bv[nf];
                }
    } else if (MODE == 1) {
        // wave's 64 cols == one head; row-of-64 lives in 16 lanes x 4 nf regs
#pragma unroll
        for (int mf = 0; mf < MF; ++mf)
#pragma unroll
            for (int r = 0; r < 4; ++r) {
                float ss = 0.f;
#pragma unroll
                for (int nf = 0; nf < 4; ++nf) {
                    float v = acc[mf][nf][r] + bv[nf];
                    acc[mf][nf][r] = v;
                    ss += v * v;
                }
                ss += __shfl_xor(ss, 1);
                ss += __shfl_xor(ss, 2);
                ss += __shfl_xor(ss, 4);
                ss += __shfl_xor(ss, 8);
                float inv = rsqrtf(ss + 1e-8f);
                int mg = m0 + wm * (BM / 2) + mf * 16 + quad * 4 + r;
                int b  = mg >> 11;
                int s  = mg & 2047;
#pragma unroll
                for (int nf = 0; nf < 4; ++nf) {
                    int ng = n0 + wn * 64 + nf * 16 + lc;
                    int h = ng >> 6, d = ng & 63;
                    out[(((size_t)(b * N_HEADS + h)) * SEQ + s) * D_K + d] =
                        f2bf(acc[mf][nf][r] * inv);
                }
            }
    } else {
        // MODE 2: transpose wave's 64(s)x64(d) tile through per-wave LDS
        // region [64 d][stride 72]. Block barrier first: other waves may
        // still be reading buf1 which these regions overlap.
        __syncthreads();
        ushort_t* vt = smem + wave * (64 * 72);
#pragma unroll
        for (int mf = 0; mf < 4; ++mf)
#pragma unroll
            for (int nf = 0; nf < 4; ++nf) {
                us4 p;
#pragma unroll
                for (int r = 0; r < 4; ++r) p[r] = f2bf(acc[mf][nf][r] + bv[nf]);
                *(us4*)(vt + (nf * 16 + lc) * 72 + mf * 16 + quad * 4) = p;
            }
        WAIT_LGKM0;   // wave-private region: wave-local fence suffices
#pragma unroll
        for (int r = 0; r < 8; ++r) {
            int d  = r * 8 + (lane >> 3);
            int so = (lane & 7) * 8;
            uint4 val = *(const uint4*)(vt + d * 72 + so);
            int mg = m0 + wm * 64 + so;
            int b  = mg >> 11;
            int s  = mg & 2047;
            int ng = n0 + wn * 64 + d;
            int h = ng >> 6, dh = ng & 63;
            *(uint4*)(out + (((size_t)(b * N_HEADS + h)) * D_K + dh) * SEQ + s) = val;
        }
    }
}

// fused Q/K/V projections: grid (x=M 32, y=N 8, z=3). id%8 = M-stripe ->
// each XCD keeps its A stripes L2-resident (the big, high-reuse operand).
__global__ __launch_bounds__(256) void qkv_kernel(
    const ushort_t* __restrict__ Qb, const ushort_t* __restrict__ Kb,
    const ushort_t* __restrict__ Vb,
    const ushort_t* __restrict__ Wq, const ushort_t* __restrict__ Wk,
    const ushort_t* __restrict__ Wv,
    const ushort_t* __restrict__ bq, const ushort_t* __restrict__ bk,
    const ushort_t* __restrict__ bv,
    ushort_t* __restrict__ qn, ushort_t* __restrict__ kn,
    ushort_t* __restrict__ vT)
{
    __shared__ __align__(16) ushort_t smem[2 * (128 + 128) * 64];  // 64 KB
    const int z = blockIdx.z;
    if (z == 0)
        gemm_body<128, 1>(smem, Qb, Wq, bq, qn, nullptr, blockIdx.x, blockIdx.y);
    else if (z == 1)
        gemm_body<128, 1>(smem, Kb, Wk, bk, kn, nullptr, blockIdx.x, blockIdx.y);
    else
        gemm_body<128, 2>(smem, Vb, Wv, bv, vT, nullptr, blockIdx.x, blockIdx.y);
}

// output projection: BM=64, grid (x=M 64, y=N 8)
__global__ __launch_bounds__(256) void wo_kernel(
    const ushort_t* __restrict__ A, const ushort_t* __restrict__ W,
    const ushort_t* __restrict__ bias, float* __restrict__ outf)
{
    __shared__ __align__(16) ushort_t smem[2 * (64 + 128) * 64];   // 48 KB
    gemm_body<64, 0>(smem, A, W, bias, nullptr, outf, blockIdx.x, blockIdx.y);
}

// ---------------------------------------------------------------------------
// Attention (R8 config): per (b,h): out = (qn kn^T)^2 v.
// Grid (x=bh 32, y=qt 16) -> 512 blocks; bh%8 pins a head to one XCD's L2.
// 128 q/block. QK^T: wave w owns j-slice [w*16,+16) -> shared P[128q][64j]
// (8B XOR swizzle). PV: wave w owns q-slice [w*32,+32), K=32 over full 64 j
// (aa assembled from 2x uint2). Epilogue: full-line stores per wave.
// ---------------------------------------------------------------------------
__global__ __launch_bounds__(256) void attn_kernel(
    const ushort_t* __restrict__ qn,
    const ushort_t* __restrict__ kn,
    const ushort_t* __restrict__ vT,
    ushort_t* __restrict__ attn_out)
{
    // staging buf i at smem+i*8192: kst [64 j][64 dk] + vst [64 d][64 j]
    __shared__ __align__(16) ushort_t smem[2 * 8192];   // 32 KB
    __shared__ __align__(16) ushort_t Pl[128 * 64];     // 16 KB, swizzled

    const int t    = threadIdx.x;
    const int wave = t >> 6;
    const int lane = t & 63;
    const int quad = lane >> 4;
    const int lc   = lane & 15;
    const int bh   = blockIdx.x;       // 0..31 (bh%8 -> XCD pin)
    const int qt   = blockIdx.y;       // 0..15
    const int b    = bh >> 4;
    const int h    = bh & 15;

    const ushort_t* qb = qn + (size_t)bh * SEQ * D_K;
    const ushort_t* kb = kn + (size_t)bh * SEQ * D_K;
    const ushort_t* vb = vT + (size_t)bh * D_K * SEQ;
    const int q0 = qt * 128;

    // Q B-frags for all 8 q-tiles of this block, reused over 32 k-tiles
    s16x8 qf[8][2];
#pragma unroll
    for (int mf = 0; mf < 8; ++mf)
#pragma unroll
        for (int ks = 0; ks < 2; ++ks)
            qf[mf][ks] = *(const s16x8*)(qb + (size_t)(q0 + mf * 16 + lc) * D_K +
                                         ks * 32 + quad * 8);

    f32x4 oacc[2][4];                  // wave's q-slice [32 q][64 d]
    const f32x4 zero = {0.f, 0.f, 0.f, 0.f};
#pragma unroll
    for (int mf = 0; mf < 2; ++mf)
#pragma unroll
        for (int df = 0; df < 4; ++df) oacc[mf][df] = zero;

    auto stage = [&](int buf, int j0) {
        ushort_t* kst = smem + buf * 8192;
        ushort_t* vst = kst + 4096;
#pragma unroll
        for (int c = 0; c < 2; ++c) {
            int idx = c * 256 + t;
            int row = idx >> 3, phys = idx & 7;
            int col = (phys ^ (row & 7)) * 8;
            gload_lds16(kb + (size_t)(j0 + row) * D_K + col, kst + idx * 8);
            gload_lds16(vb + (size_t)row * SEQ + j0 + col, vst + idx * 8);
        }
    };

    // QK^T phase: wave's 16-j slice vs all 128 q -> P
    auto qk = [&](int buf) {
        ushort_t* kst = smem + buf * 8192;
        s16x8 ak[2];
#pragma unroll
        for (int ks = 0; ks < 2; ++ks)
            ak[ks] = *(const s16x8*)(kst + (wave * 16 + lc) * 64 +
                                     (((ks * 4 + quad) ^ (lc & 7)) * 8));
        const int log8 = wave * 4 + quad;   // 8B chunk of wave's j in a P row
#pragma unroll
        for (int mf = 0; mf < 8; ++mf) {
            f32x4 st = zero;   // S^T tile: lane = [j=quad*4+r][q=lc]
#pragma unroll
            for (int ks = 0; ks < 2; ++ks)
                st = __builtin_amdgcn_mfma_f32_16x16x32_bf16(ak[ks], qf[mf][ks], st, 0, 0, 0);
            uint2 w;
            w.x = pack2bf(st[0] * st[0], st[1] * st[1]);
            w.y = pack2bf(st[2] * st[2], st[3] * st[3]);
            const int row = mf * 16 + lc;
            *(uint2*)(Pl + row * 64 + (log8 ^ lc) * 4) = w;
        }
    };

    // PV phase: wave's 32-q slice, K=32 over the full 64-j tile
    auto pv = [&](int buf) {
        ushort_t* vst = smem + buf * 8192 + 4096;
        s16x8 bvf[4][2];
#pragma unroll
        for (int df = 0; df < 4; ++df)
#pragma unroll
            for (int ks = 0; ks < 2; ++ks)
                bvf[df][ks] = *(const s16x8*)(vst + (df * 16 + lc) * 64 +
                                              (((ks * 4 + quad) ^ (lc & 7)) * 8));
        s16x8 aa[2][2];
#pragma unroll
        for (int mfp = 0; mfp < 2; ++mfp)
#pragma unroll
            for (int ks = 0; ks < 2; ++ks) {
                const int row = wave * 32 + mfp * 16 + lc;
                const int l0  = ks * 8 + quad * 2;
                uint2 lo = *(const uint2*)(Pl + row * 64 + ((l0 ^ lc) * 4));
                uint2 hi = *(const uint2*)(Pl + row * 64 + (((l0 + 1) ^ lc) * 4));
                union { unsigned int u[4]; s16x8 v; } m;
                m.u[0] = lo.x; m.u[1] = lo.y; m.u[2] = hi.x; m.u[3] = hi.y;
                aa[mfp][ks] = m.v;
            }
#pragma unroll
        for (int mfp = 0; mfp < 2; ++mfp)
#pragma unroll
            for (int df = 0; df < 4; ++df)
#pragma unroll
                for (int ks = 0; ks < 2; ++ks)
                    oacc[mfp][df] = __builtin_amdgcn_mfma_f32_16x16x32_bf16(
                        aa[mfp][ks], bvf[df][ks], oacc[mfp][df], 0, 0, 0);
    };

    constexpr int NT = 32;
    stage(0, 0);
    stage(1, 64);
    for (int it = 0; it < NT; ++it) {
        if (it < NT - 1) { WAIT_VM(4); } else { WAIT_VM(0); }
        BARRIER;                       // k/v tile `it` landed everywhere
        qk(it & 1);
        WAIT_LGKM0;
        BARRIER;                       // P complete; kst reads done
        pv(it & 1);
        if (it < NT - 2) {
            WAIT_LGKM0;
            BARRIER;                   // vst + P reads done -> buf reusable
            stage(it & 1, (it + 2) * 64);
        } else if (it == NT - 2) {
            WAIT_LGKM0;
            BARRIER;                   // protect P for the last qk()
        }
    }

    // store wave's [32 q][64 d] to (B,S,D) head-interleaved bf16.
    // Each wave writes FULL 128B lines (all 64 d per s) -> clean
    // write-combining, no write-allocate RMW (R9/R10 lesson).
#pragma unroll
    for (int mfp = 0; mfp < 2; ++mfp)
#pragma unroll
        for (int df = 0; df < 4; ++df)
#pragma unroll
            for (int r = 0; r < 4; ++r) {
                int s = q0 + wave * 32 + mfp * 16 + quad * 4 + r;
                int d = df * 16 + lc;
                attn_out[((size_t)(b * SEQ + s)) * D_MODEL + h * D_K + d] =
                    f2bf(oacc[mfp][df][r]);
            }
}

extern "C" void kernel_launch(void* const* d_in, const int* in_sizes, int n_in,
                              void* d_out, int out_size, void* d_ws, size_t ws_size,
                              hipStream_t stream)
{
    const float* Qf   = (const float*)d_in[0];
    const float* Kf   = (const float*)d_in[1];
    const float* Vf   = (const float*)d_in[2];
    const float* Wqf  = (const float*)d_in[3];
    const float* Wqbf = (const float*)d_in[4];
    const float* Wkf  = (const float*)d_in[5];
    const float* Wkbf = (const float*)d_in[6];
    const float* Wvf  = (const float*)d_in[7];
    const float* Wvbf = (const float*)d_in[8];
    const float* Wof  = (const float*)d_in[9];
    const float* Wobf = (const float*)d_in[10];

    const size_t NM = (size_t)M_TOT * D_MODEL;
    const size_t NW = (size_t)D_MODEL * D_MODEL;
    const size_t NB = D_MODEL;

    ushort_t* p = (ushort_t*)d_ws;
    ushort_t* Qb  = p;  p += NM;
    ushort_t* Kb  = p;  p += NM;
    ushort_t* Vb  = p;  p += NM;
    ushort_t* Wq  = p;  p += NW;
    ushort_t* Wk  = p;  p += NW;
    ushort_t* Wv  = p;  p += NW;
    ushort_t* Wo  = p;  p += NW;
    ushort_t* bq  = p;  p += NB;
    ushort_t* bk  = p;  p += NB;
    ushort_t* bvv = p;  p += NB;
    ushort_t* bo  = p;  p += NB;
    ushort_t* qn  = p;  p += NM;   // (B,H,S,DK)
    ushort_t* kn  = p;  p += NM;   // (B,H,S,DK)
    ushort_t* vT  = p;  p += NM;   // (B,H,DK,S)
    ushort_t* ao  = p;  p += NM;   // (B,S,D)

    ConvArgs ca;
    ca.src[0] = Qf;   ca.dst[0] = Qb;  ca.n[0] = (int)NM;
    ca.src[1] = Kf;   ca.dst[1] = Kb;  ca.n[1] = (int)NM;
    ca.src[2] = Vf;   ca.dst[2] = Vb;  ca.n[2] = (int)NM;
    ca.src[3] = Wqf;  ca.dst[3] = Wq;  ca.n[3] = (int)NW;
    ca.src[4] = Wkf;  ca.dst[4] = Wk;  ca.n[4] = (int)NW;
    ca.src[5] = Wvf;  ca.dst[5] = Wv;  ca.n[5] = (int)NW;
    ca.src[6] = Wof;  ca.dst[6] = Wo;  ca.n[6] = (int)NW;
    ca.src[7] = Wqbf; ca.dst[7] = bq;  ca.n[7] = (int)NB;
    ca.src[8] = Wkbf; ca.dst[8] = bk;  ca.n[8] = (int)NB;
    ca.src[9] = Wvbf; ca.dst[9] = bvv; ca.n[9] = (int)NB;
    ca.src[10] = Wobf; ca.dst[10] = bo; ca.n[10] = (int)NB;

    dim3 blk(256);
    convert_kernel<<<dim3((unsigned)(NM / (256 * 4)), 11), blk, 0, stream>>>(ca);

    qkv_kernel<<<dim3(M_TOT / 128, D_MODEL / 128, 3), blk, 0, stream>>>(
        Qb, Kb, Vb, Wq, Wk, Wv, bq, bk, bvv, qn, kn, vT);
    attn_kernel<<<dim3(BATCH * N_HEADS, SEQ / 128), blk, 0, stream>>>(qn, kn, vT, ao);
    wo_kernel<<<dim3(M_TOT / 64, D_MODEL / 128), blk, 0, stream>>>(
        ao, Wo, bo, (float*)d_out);
}